// Round 3
// baseline (294.300 us; speedup 1.0000x reference)
//
#include <hip/hip_runtime.h>

#define HH 16
#define RED_VALS 34   // 16 top(g.p) + 16 (y.p) + cur + gg
#define NBLK 2048

// Fused 33-stream reduction, branch-free inner loop (structure cloned from the
// output kernel, which hits ~6.4 TB/s effective). cur/gg come from 2 extra
// loads of row hidx (same cachelines as the row loop -> L1 hits).
__global__ __launch_bounds__(256) void lbfgs_reduce(
    const float* __restrict__ p, const float* __restrict__ y,
    const float* __restrict__ g, const int* __restrict__ idxp,
    float* __restrict__ partials, int n) {
  const int is = idxp[0];
  const int hidx = ((is - 1) % HH + HH) % HH;

  float acc[RED_VALS];
#pragma unroll
  for (int j = 0; j < RED_VALS; ++j) acc[j] = 0.f;

  const int tid = blockIdx.x * blockDim.x + threadIdx.x;
  const int nth = gridDim.x * blockDim.x;
  const int nchunk = n >> 2;
  const float4* __restrict__ p4  = reinterpret_cast<const float4*>(p);
  const float4* __restrict__ gh4 = reinterpret_cast<const float4*>(g + (size_t)hidx * n);
  const float4* __restrict__ yh4 = reinterpret_cast<const float4*>(y + (size_t)hidx * n);

  for (int c = tid; c < nchunk; c += nth) {
    float4 pv  = p4[c];
    float4 ghv = gh4[c];
    float4 yhv = yh4[c];
    acc[32] += yhv.x * ghv.x + yhv.y * ghv.y + yhv.z * ghv.z + yhv.w * ghv.w;
    acc[33] += ghv.x * ghv.x + ghv.y * ghv.y + ghv.z * ghv.z + ghv.w * ghv.w;
#pragma unroll
    for (int i = 0; i < HH; ++i) {
      const float4 gv = reinterpret_cast<const float4*>(g + (size_t)i * n)[c];
      const float4 yv = reinterpret_cast<const float4*>(y + (size_t)i * n)[c];
      acc[i]      += gv.x * pv.x + gv.y * pv.y + gv.z * pv.z + gv.w * pv.w;
      acc[HH + i] += yv.x * pv.x + yv.y * pv.y + yv.z * pv.z + yv.w * pv.w;
    }
  }
  // scalar tail (n not multiple of 4)
  for (int c = (nchunk << 2) + tid; c < n; c += nth) {
    float pv = p[c];
    float ghv = g[(size_t)hidx * n + c];
    float yhv = y[(size_t)hidx * n + c];
    acc[32] += yhv * ghv;
    acc[33] += ghv * ghv;
#pragma unroll
    for (int i = 0; i < HH; ++i) {
      acc[i]      += g[(size_t)i * n + c] * pv;
      acc[HH + i] += y[(size_t)i * n + c] * pv;
    }
  }
  // wave(64) shuffle reduce, then cross-wave via LDS
#pragma unroll
  for (int j = 0; j < RED_VALS; ++j) {
    float v = acc[j];
#pragma unroll
    for (int off = 32; off > 0; off >>= 1) v += __shfl_down(v, off);
    acc[j] = v;
  }
  __shared__ float red[4][RED_VALS];
  const int wave = threadIdx.x >> 6, lane = threadIdx.x & 63;
  if (lane == 0) {
#pragma unroll
    for (int j = 0; j < RED_VALS; ++j) red[wave][j] = acc[j];
  }
  __syncthreads();
  if (threadIdx.x < RED_VALS) {
    float s = red[0][threadIdx.x] + red[1][threadIdx.x] +
              red[2][threadIdx.x] + red[3][threadIdx.x];
    partials[(size_t)blockIdx.x * RED_VALS + threadIdx.x] = s;
  }
}

__global__ __launch_bounds__(256) void lbfgs_solve(
    const float* __restrict__ partials, int nblk,
    const float* __restrict__ Lmat, const float* __restrict__ diag,
    const float* __restrict__ sinner, const int* __restrict__ idxp,
    float* __restrict__ coeff) {
  __shared__ float sums[RED_VALS];
  __shared__ float wred[RED_VALS][4];
  const int wave = threadIdx.x >> 6, lane = threadIdx.x & 63;
  for (int j = 0; j < RED_VALS; ++j) {
    float v = 0.f;
    for (int b = threadIdx.x; b < nblk; b += 256)
      v += partials[(size_t)b * RED_VALS + j];
#pragma unroll
    for (int off = 32; off > 0; off >>= 1) v += __shfl_down(v, off);
    if (lane == 0) wred[j][wave] = v;
  }
  __syncthreads();
  if (threadIdx.x < RED_VALS)
    sums[threadIdx.x] = wred[threadIdx.x][0] + wred[threadIdx.x][1] +
                        wred[threadIdx.x][2] + wred[threadIdx.x][3];
  __syncthreads();

  __shared__ float Lsh[HH][HH];
  __shared__ float dd[HH], sqd[HH];
  __shared__ float Jsq[HH][HH];
  __shared__ float gamma_s;
  __shared__ float x[2 * HH];
  {
    int i = threadIdx.x >> 4, j = threadIdx.x & 15;
    if (threadIdx.x < 256) Lsh[i][j] = Lmat[i * HH + j];
  }
  if (threadIdx.x < HH) {
    float dv = diag[threadIdx.x];
    float ddv = (dv == 0.f) ? 1.f : dv;
    dd[threadIdx.x] = ddv;
    sqd[threadIdx.x] = sqrtf(ddv);
  }
  if (threadIdx.x == 0) {
    float cur = sums[32], gg = sums[33];
    gamma_s = (cur > 0.f) ? (gg / cur) : 1.f;
  }
  __syncthreads();
  {
    int i = threadIdx.x >> 4, j = threadIdx.x & 15;
    float v = gamma_s * sinner[i * HH + j];
#pragma unroll
    for (int k = 0; k < HH; ++k) v += Lsh[i][k] * Lsh[j][k] / dd[k];
    Jsq[i][j] = v;
  }
  __syncthreads();
  if (threadIdx.x == 0) {
    // in-place lower Cholesky of Jsq (16x16, serial — tiny)
    for (int c = 0; c < HH; ++c) {
      float s = Jsq[c][c];
      for (int k = 0; k < c; ++k) s -= Jsq[c][k] * Jsq[c][k];
      float dv = sqrtf(s);
      Jsq[c][c] = dv;
      float inv = 1.f / dv;
      for (int r = c + 1; r < HH; ++r) {
        float s2 = Jsq[r][c];
        for (int k = 0; k < c; ++k) s2 -= Jsq[r][k] * Jsq[c][k];
        Jsq[r][c] = s2 * inv;
      }
    }
    const int is = idxp[0];
    const int sh = (is <= HH) ? 0 : (is % HH);
    const float gamma = gamma_s;
    // build rolled descent vector
    for (int k = 0; k < HH; ++k) {
      x[k]      = sums[(k + sh) & (HH - 1)];
      x[HH + k] = gamma * sums[HH + ((k + sh) & (HH - 1))];
    }
    // forward solve: low_tri = [[diag(sqd), 0], [-L/sqd_col, J]]
    for (int i = 0; i < HH; ++i) x[i] /= sqd[i];
    for (int i = 0; i < HH; ++i) {
      float s = x[HH + i];
      for (int j = 0; j < HH; ++j) s += (Lsh[i][j] / sqd[j]) * x[j];
      for (int j = 0; j < i; ++j) s -= Jsq[i][j] * x[HH + j];
      x[HH + i] = s / Jsq[i][i];
    }
    // backward solve: upper = low^T with top h rows negated
    for (int i = HH - 1; i >= 0; --i) {
      float s = x[HH + i];
      for (int j = i + 1; j < HH; ++j) s -= Jsq[j][i] * x[HH + j];
      x[HH + i] = s / Jsq[i][i];
    }
    for (int i = 0; i < HH; ++i) {
      float s = x[i];
      for (int j = 0; j < HH; ++j) s -= (Lsh[j][i] / sqd[i]) * x[HH + j];
      x[i] = s / (-sqd[i]);
    }
    // un-roll and emit coefficients (beta pre-scaled by gamma)
    coeff[0] = gamma;
    for (int k = 0; k < HH; ++k) {
      coeff[1 + k]      = x[(k - sh + HH) & (HH - 1)];
      coeff[1 + HH + k] = gamma * x[HH + ((k - sh + HH) & (HH - 1))];
    }
  }
}

// Grid-stride steps in REVERSE: reduce swept ascending, so L3 holds the
// high-address tail; reading high->low harvests it, and finishing at low
// addresses re-primes L3 for the next replay's ascending reduce.
__global__ __launch_bounds__(256) void lbfgs_output(
    const float* __restrict__ p, const float* __restrict__ y,
    const float* __restrict__ g, const float* __restrict__ coeff,
    float* __restrict__ out, int n) {
  const float gamma = coeff[0];
  float a[HH], b[HH];
#pragma unroll
  for (int i = 0; i < HH; ++i) {
    a[i] = coeff[1 + i];
    b[i] = coeff[1 + HH + i];
  }
  const int tid = blockIdx.x * blockDim.x + threadIdx.x;
  const int nth = gridDim.x * blockDim.x;
  const int nchunk = n >> 2;
  const float4* __restrict__ p4 = reinterpret_cast<const float4*>(p);
  float4* __restrict__ out4 = reinterpret_cast<float4*>(out);

  // scalar tail first (highest addresses)
  for (int c = (nchunk << 2) + tid; c < n; c += nth) {
    float pv = p[c];
    float o = gamma * pv;
#pragma unroll
    for (int i = 0; i < HH; ++i)
      o -= a[i] * g[(size_t)i * n + c] + b[i] * y[(size_t)i * n + c];
    out[c] = o;
  }
  const int nsteps = (nchunk + nth - 1) / nth;
  for (int s = nsteps - 1; s >= 0; --s) {
    const int c = tid + s * nth;
    if (c >= nchunk) continue;
    float4 pv = p4[c];
    float ox = gamma * pv.x, oy = gamma * pv.y;
    float oz = gamma * pv.z, ow = gamma * pv.w;
#pragma unroll
    for (int i = 0; i < HH; ++i) {
      const float4 gv = reinterpret_cast<const float4*>(g + (size_t)i * n)[c];
      const float4 yv = reinterpret_cast<const float4*>(y + (size_t)i * n)[c];
      ox -= a[i] * gv.x + b[i] * yv.x;
      oy -= a[i] * gv.y + b[i] * yv.y;
      oz -= a[i] * gv.z + b[i] * yv.z;
      ow -= a[i] * gv.w + b[i] * yv.w;
    }
    out4[c] = make_float4(ox, oy, oz, ow);
  }
}

extern "C" void kernel_launch(void* const* d_in, const int* in_sizes, int n_in,
                              void* d_out, int out_size, void* d_ws, size_t ws_size,
                              hipStream_t stream) {
  const float* p      = (const float*)d_in[0];
  const float* y      = (const float*)d_in[1];
  const float* g      = (const float*)d_in[2];
  const float* Lmat   = (const float*)d_in[3];
  const float* diag   = (const float*)d_in[4];
  const float* sinner = (const float*)d_in[5];
  const int*   idxp   = (const int*)d_in[6];
  float* out = (float*)d_out;
  float* wsf = (float*)d_ws;
  const int n = in_sizes[0];

  int nblk = NBLK;
  size_t need = ((size_t)nblk * RED_VALS + 64) * sizeof(float);
  if (ws_size < need) {
    long avail = (long)(ws_size / sizeof(float)) - 64;
    nblk = (int)(avail / RED_VALS);
    if (nblk < 1) nblk = 1;
    if (nblk > NBLK) nblk = NBLK;
  }
  float* partials = wsf;
  float* coeff = wsf + (size_t)nblk * RED_VALS;

  lbfgs_reduce<<<dim3(nblk), dim3(256), 0, stream>>>(p, y, g, idxp, partials, n);
  lbfgs_solve<<<dim3(1), dim3(256), 0, stream>>>(partials, nblk, Lmat, diag,
                                                 sinner, idxp, coeff);
  lbfgs_output<<<dim3(NBLK), dim3(256), 0, stream>>>(p, y, g, coeff, out, n);
}

// Round 4
// 253.441 us; speedup vs baseline: 1.1612x; 1.1612x over previous
//
#include <hip/hip_runtime.h>

#define HH 16
#define RED_VALS 34   // 16 top(g.p) + 16 (y.p) + cur + gg
#define RGX 1024      // x-blocks per row-group
#define OUTBLK 2048

// Reduction: grid.y = 5 groups. Groups 0..3 each own 4 history rows and
// compute 8 dot products vs p (9 load streams, 8 persistent accumulators —
// enough registers left to keep a full iteration's loads in flight).
// Group 4 computes cur = y_h.g_h and gg = g_h.g_h (2 streams).
__global__ __launch_bounds__(256) void lbfgs_reduce(
    const float* __restrict__ p, const float* __restrict__ y,
    const float* __restrict__ g, const int* __restrict__ idxp,
    float* __restrict__ partials, int n) {
  const int grp = blockIdx.y;
  const int tid = blockIdx.x * blockDim.x + threadIdx.x;
  const int nth = gridDim.x * blockDim.x;
  const int nchunk = n >> 2;

  float acc[8];
#pragma unroll
  for (int j = 0; j < 8; ++j) acc[j] = 0.f;

  if (grp < 4) {
    const float4* __restrict__ p4 = reinterpret_cast<const float4*>(p);
    const float4* __restrict__ g0 = reinterpret_cast<const float4*>(g + (size_t)(4 * grp + 0) * n);
    const float4* __restrict__ g1 = reinterpret_cast<const float4*>(g + (size_t)(4 * grp + 1) * n);
    const float4* __restrict__ g2 = reinterpret_cast<const float4*>(g + (size_t)(4 * grp + 2) * n);
    const float4* __restrict__ g3 = reinterpret_cast<const float4*>(g + (size_t)(4 * grp + 3) * n);
    const float4* __restrict__ y0 = reinterpret_cast<const float4*>(y + (size_t)(4 * grp + 0) * n);
    const float4* __restrict__ y1 = reinterpret_cast<const float4*>(y + (size_t)(4 * grp + 1) * n);
    const float4* __restrict__ y2 = reinterpret_cast<const float4*>(y + (size_t)(4 * grp + 2) * n);
    const float4* __restrict__ y3 = reinterpret_cast<const float4*>(y + (size_t)(4 * grp + 3) * n);
    for (int c = tid; c < nchunk; c += nth) {
      float4 pv = p4[c];
      float4 gv0 = g0[c], gv1 = g1[c], gv2 = g2[c], gv3 = g3[c];
      float4 yv0 = y0[c], yv1 = y1[c], yv2 = y2[c], yv3 = y3[c];
      acc[0] += gv0.x * pv.x + gv0.y * pv.y + gv0.z * pv.z + gv0.w * pv.w;
      acc[1] += gv1.x * pv.x + gv1.y * pv.y + gv1.z * pv.z + gv1.w * pv.w;
      acc[2] += gv2.x * pv.x + gv2.y * pv.y + gv2.z * pv.z + gv2.w * pv.w;
      acc[3] += gv3.x * pv.x + gv3.y * pv.y + gv3.z * pv.z + gv3.w * pv.w;
      acc[4] += yv0.x * pv.x + yv0.y * pv.y + yv0.z * pv.z + yv0.w * pv.w;
      acc[5] += yv1.x * pv.x + yv1.y * pv.y + yv1.z * pv.z + yv1.w * pv.w;
      acc[6] += yv2.x * pv.x + yv2.y * pv.y + yv2.z * pv.z + yv2.w * pv.w;
      acc[7] += yv3.x * pv.x + yv3.y * pv.y + yv3.z * pv.z + yv3.w * pv.w;
    }
    // scalar tail
    for (int c = (nchunk << 2) + tid; c < n; c += nth) {
      float pv = p[c];
#pragma unroll
      for (int i = 0; i < 4; ++i) {
        acc[i]     += g[(size_t)(4 * grp + i) * n + c] * pv;
        acc[4 + i] += y[(size_t)(4 * grp + i) * n + c] * pv;
      }
    }
  } else {
    const int is = idxp[0];
    const int hidx = ((is - 1) % HH + HH) % HH;
    const float4* __restrict__ gh4 = reinterpret_cast<const float4*>(g + (size_t)hidx * n);
    const float4* __restrict__ yh4 = reinterpret_cast<const float4*>(y + (size_t)hidx * n);
    for (int c = tid; c < nchunk; c += nth) {
      float4 gv = gh4[c], yv = yh4[c];
      acc[0] += yv.x * gv.x + yv.y * gv.y + yv.z * gv.z + yv.w * gv.w;
      acc[1] += gv.x * gv.x + gv.y * gv.y + gv.z * gv.z + gv.w * gv.w;
    }
    for (int c = (nchunk << 2) + tid; c < n; c += nth) {
      float gv = g[(size_t)hidx * n + c], yv = y[(size_t)hidx * n + c];
      acc[0] += yv * gv;
      acc[1] += gv * gv;
    }
  }

  // block-reduce 8 values: wave shuffle then cross-wave LDS
#pragma unroll
  for (int j = 0; j < 8; ++j) {
    float v = acc[j];
#pragma unroll
    for (int off = 32; off > 0; off >>= 1) v += __shfl_down(v, off);
    acc[j] = v;
  }
  __shared__ float red[4][8];
  const int wave = threadIdx.x >> 6, lane = threadIdx.x & 63;
  if (lane == 0) {
#pragma unroll
    for (int j = 0; j < 8; ++j) red[wave][j] = acc[j];
  }
  __syncthreads();
  if (threadIdx.x < 8) {
    float s = red[0][threadIdx.x] + red[1][threadIdx.x] +
              red[2][threadIdx.x] + red[3][threadIdx.x];
    partials[((size_t)grp * gridDim.x + blockIdx.x) * 8 + threadIdx.x] = s;
  }
}

__global__ __launch_bounds__(256) void lbfgs_solve(
    const float* __restrict__ partials, int nblkx,
    const float* __restrict__ Lmat, const float* __restrict__ diag,
    const float* __restrict__ sinner, const int* __restrict__ idxp,
    float* __restrict__ coeff) {
  __shared__ float sums[RED_VALS];
  __shared__ float wred[RED_VALS][4];
  const int wave = threadIdx.x >> 6, lane = threadIdx.x & 63;
  for (int j = 0; j < RED_VALS; ++j) {
    // map logical value j -> (group, slot) in partials[grp][blk][8]
    int grpi, slot;
    if (j < HH)           { grpi = j >> 2;         slot = j & 3; }
    else if (j < 2 * HH)  { int r = j - HH; grpi = r >> 2; slot = 4 + (r & 3); }
    else                  { grpi = 4;              slot = j - 32; }
    float v = 0.f;
    for (int b = threadIdx.x; b < nblkx; b += 256)
      v += partials[((size_t)grpi * nblkx + b) * 8 + slot];
#pragma unroll
    for (int off = 32; off > 0; off >>= 1) v += __shfl_down(v, off);
    if (lane == 0) wred[j][wave] = v;
  }
  __syncthreads();
  if (threadIdx.x < RED_VALS)
    sums[threadIdx.x] = wred[threadIdx.x][0] + wred[threadIdx.x][1] +
                        wred[threadIdx.x][2] + wred[threadIdx.x][3];
  __syncthreads();

  __shared__ float Lsh[HH][HH];
  __shared__ float dd[HH], sqd[HH];
  __shared__ float Jsq[HH][HH];
  __shared__ float gamma_s;
  __shared__ float x[2 * HH];
  {
    int i = threadIdx.x >> 4, j = threadIdx.x & 15;
    if (threadIdx.x < 256) Lsh[i][j] = Lmat[i * HH + j];
  }
  if (threadIdx.x < HH) {
    float dv = diag[threadIdx.x];
    float ddv = (dv == 0.f) ? 1.f : dv;
    dd[threadIdx.x] = ddv;
    sqd[threadIdx.x] = sqrtf(ddv);
  }
  if (threadIdx.x == 0) {
    float cur = sums[32], gg = sums[33];
    gamma_s = (cur > 0.f) ? (gg / cur) : 1.f;
  }
  __syncthreads();
  {
    int i = threadIdx.x >> 4, j = threadIdx.x & 15;
    float v = gamma_s * sinner[i * HH + j];
#pragma unroll
    for (int k = 0; k < HH; ++k) v += Lsh[i][k] * Lsh[j][k] / dd[k];
    Jsq[i][j] = v;
  }
  __syncthreads();
  if (threadIdx.x == 0) {
    // in-place lower Cholesky of Jsq (16x16, serial — tiny)
    for (int c = 0; c < HH; ++c) {
      float s = Jsq[c][c];
      for (int k = 0; k < c; ++k) s -= Jsq[c][k] * Jsq[c][k];
      float dv = sqrtf(s);
      Jsq[c][c] = dv;
      float inv = 1.f / dv;
      for (int r = c + 1; r < HH; ++r) {
        float s2 = Jsq[r][c];
        for (int k = 0; k < c; ++k) s2 -= Jsq[r][k] * Jsq[c][k];
        Jsq[r][c] = s2 * inv;
      }
    }
    const int is = idxp[0];
    const int sh = (is <= HH) ? 0 : (is % HH);
    const float gamma = gamma_s;
    // build rolled descent vector
    for (int k = 0; k < HH; ++k) {
      x[k]      = sums[(k + sh) & (HH - 1)];
      x[HH + k] = gamma * sums[HH + ((k + sh) & (HH - 1))];
    }
    // forward solve: low_tri = [[diag(sqd), 0], [-L/sqd_col, J]]
    for (int i = 0; i < HH; ++i) x[i] /= sqd[i];
    for (int i = 0; i < HH; ++i) {
      float s = x[HH + i];
      for (int j = 0; j < HH; ++j) s += (Lsh[i][j] / sqd[j]) * x[j];
      for (int j = 0; j < i; ++j) s -= Jsq[i][j] * x[HH + j];
      x[HH + i] = s / Jsq[i][i];
    }
    // backward solve: upper = low^T with top h rows negated
    for (int i = HH - 1; i >= 0; --i) {
      float s = x[HH + i];
      for (int j = i + 1; j < HH; ++j) s -= Jsq[j][i] * x[HH + j];
      x[HH + i] = s / Jsq[i][i];
    }
    for (int i = 0; i < HH; ++i) {
      float s = x[i];
      for (int j = 0; j < HH; ++j) s -= (Lsh[j][i] / sqd[i]) * x[HH + j];
      x[i] = s / (-sqd[i]);
    }
    // un-roll and emit coefficients (beta pre-scaled by gamma)
    coeff[0] = gamma;
    for (int k = 0; k < HH; ++k) {
      coeff[1 + k]      = x[(k - sh + HH) & (HH - 1)];
      coeff[1 + HH + k] = gamma * x[HH + ((k - sh + HH) & (HH - 1))];
    }
  }
}

// Plain ascending grid-stride (the R2 version that ran ~83 us).
__global__ __launch_bounds__(256) void lbfgs_output(
    const float* __restrict__ p, const float* __restrict__ y,
    const float* __restrict__ g, const float* __restrict__ coeff,
    float* __restrict__ out, int n) {
  const float gamma = coeff[0];
  float a[HH], b[HH];
#pragma unroll
  for (int i = 0; i < HH; ++i) {
    a[i] = coeff[1 + i];
    b[i] = coeff[1 + HH + i];
  }
  const int tid = blockIdx.x * blockDim.x + threadIdx.x;
  const int nth = gridDim.x * blockDim.x;
  const int nchunk = n >> 2;
  const float4* __restrict__ p4 = reinterpret_cast<const float4*>(p);
  float4* __restrict__ out4 = reinterpret_cast<float4*>(out);
  for (int c = tid; c < nchunk; c += nth) {
    float4 pv = p4[c];
    float ox = gamma * pv.x, oy = gamma * pv.y;
    float oz = gamma * pv.z, ow = gamma * pv.w;
#pragma unroll
    for (int i = 0; i < HH; ++i) {
      const float4 gv = reinterpret_cast<const float4*>(g + (size_t)i * n)[c];
      const float4 yv = reinterpret_cast<const float4*>(y + (size_t)i * n)[c];
      ox -= a[i] * gv.x + b[i] * yv.x;
      oy -= a[i] * gv.y + b[i] * yv.y;
      oz -= a[i] * gv.z + b[i] * yv.z;
      ow -= a[i] * gv.w + b[i] * yv.w;
    }
    out4[c] = make_float4(ox, oy, oz, ow);
  }
  for (int c = (nchunk << 2) + tid; c < n; c += nth) {
    float pv = p[c];
    float o = gamma * pv;
#pragma unroll
    for (int i = 0; i < HH; ++i)
      o -= a[i] * g[(size_t)i * n + c] + b[i] * y[(size_t)i * n + c];
    out[c] = o;
  }
}

extern "C" void kernel_launch(void* const* d_in, const int* in_sizes, int n_in,
                              void* d_out, int out_size, void* d_ws, size_t ws_size,
                              hipStream_t stream) {
  const float* p      = (const float*)d_in[0];
  const float* y      = (const float*)d_in[1];
  const float* g      = (const float*)d_in[2];
  const float* Lmat   = (const float*)d_in[3];
  const float* diag   = (const float*)d_in[4];
  const float* sinner = (const float*)d_in[5];
  const int*   idxp   = (const int*)d_in[6];
  float* out = (float*)d_out;
  float* wsf = (float*)d_ws;
  const int n = in_sizes[0];

  int gx = RGX;
  size_t need = ((size_t)5 * gx * 8 + 64) * sizeof(float);
  if (ws_size < need) {
    long avail = (long)(ws_size / sizeof(float)) - 64;
    gx = (int)(avail / (5 * 8));
    if (gx < 1) gx = 1;
    if (gx > RGX) gx = RGX;
  }
  float* partials = wsf;
  float* coeff = wsf + (size_t)5 * gx * 8;

  lbfgs_reduce<<<dim3(gx, 5), dim3(256), 0, stream>>>(p, y, g, idxp, partials, n);
  lbfgs_solve<<<dim3(1), dim3(256), 0, stream>>>(partials, gx, Lmat, diag,
                                                 sinner, idxp, coeff);
  lbfgs_output<<<dim3(OUTBLK), dim3(256), 0, stream>>>(p, y, g, coeff, out, n);
}